// Round 3
// baseline (4370.428 us; speedup 1.0000x reference)
//
#include <hip/hip_runtime.h>

// S=1024 seq, B=32 batch, H=512 hid, E=512 emb, A=256 att — ALL f32 per reference
#define Sn 1024
#define Bn 32
#define Hn 512
#define En 512
#define An 256

// ---------------- projection v2: out[b][s][a] = exp2( scale*(X[s*B+b][:] . W[a][:] + bias[a]) )
// X: [S*B][512] f32, W: [256][512] f32.
// v2: M=64 rows/block, 512 threads, double-buffered BK=8 LDS tiles, ONE barrier/chunk.
// Weight L2 traffic: 512 blocks x 512KB = 256MB (was 1GB). Loads for chunk c+1 issue
// before compute of chunk c -> L2 latency hidden under ~512 FMA-cycles.
__global__ __launch_bounds__(512) void proj_kernel(const float* __restrict__ X,
                                                   const float* __restrict__ W,
                                                   const float* __restrict__ bias,
                                                   float* __restrict__ outp){
  __shared__ float wl[2][8][256];   // [buf][k][a-col]
  __shared__ float xl[2][8][64];    // [buf][k][row]
  int tid = threadIdx.x;
  int rg = tid >> 6;                // 0..7 -> rows rg*8..+7
  int ct = tid & 63;                // cols ct*4..+3
  long r0 = (long)blockIdx.x * 64;

  // staging roles: W row = tid>>1 (256 rows x 2 k-halves); X rows by threads 0..127
  int wrow = tid >> 1, wkg = tid & 1;
  const float* wsrc = W + (long)wrow * 512 + wkg * 4;
  int xrow = tid >> 1, xkg = tid & 1;        // valid for tid<128
  const float* xsrc = X + (r0 + xrow) * 512 + xkg * 4;

  float acc[8][4];
  #pragma unroll
  for (int r = 0; r < 8; r++)
    #pragma unroll
    for (int j = 0; j < 4; j++) acc[r][j] = 0.f;

  // preload chunk 0 into buf 0
  float4 wv = *(const float4*)(wsrc);
  float4 xv;
  if (tid < 128) xv = *(const float4*)(xsrc);
  wl[0][wkg*4+0][wrow]=wv.x; wl[0][wkg*4+1][wrow]=wv.y;
  wl[0][wkg*4+2][wrow]=wv.z; wl[0][wkg*4+3][wrow]=wv.w;
  if (tid < 128){
    xl[0][xkg*4+0][xrow]=xv.x; xl[0][xkg*4+1][xrow]=xv.y;
    xl[0][xkg*4+2][xrow]=xv.z; xl[0][xkg*4+3][xrow]=xv.w;
  }
  __syncthreads();

  for (int c = 0; c < 64; c++){
    int cb = c & 1, nb = cb ^ 1;
    if (c < 63){
      wv = *(const float4*)(wsrc + (c+1)*8);
      if (tid < 128) xv = *(const float4*)(xsrc + (c+1)*8);
    }
    #pragma unroll
    for (int k = 0; k < 8; k++){
      float4 xa = *(const float4*)&xl[cb][k][rg*8];      // wave-uniform broadcast
      float4 xb = *(const float4*)&xl[cb][k][rg*8+4];
      float4 wc = *(const float4*)&wl[cb][k][ct*4];      // lane-contiguous b128
      float xr8[8] = {xa.x,xa.y,xa.z,xa.w,xb.x,xb.y,xb.z,xb.w};
      float wc4[4] = {wc.x,wc.y,wc.z,wc.w};
      #pragma unroll
      for (int r = 0; r < 8; r++)
        #pragma unroll
        for (int j = 0; j < 4; j++)
          acc[r][j] += xr8[r]*wc4[j];
    }
    if (c < 63){
      wl[nb][wkg*4+0][wrow]=wv.x; wl[nb][wkg*4+1][wrow]=wv.y;
      wl[nb][wkg*4+2][wrow]=wv.z; wl[nb][wkg*4+3][wrow]=wv.w;
      if (tid < 128){
        xl[nb][xkg*4+0][xrow]=xv.x; xl[nb][xkg*4+1][xrow]=xv.y;
        xl[nb][xkg*4+2][xrow]=xv.z; xl[nb][xkg*4+3][xrow]=xv.w;
      }
    }
    __syncthreads();
  }

  const float scale = 2.8853900817779268f;  // 2*log2(e): arg pre-scale for exp2-based tanh
  float bz[4];
  {
    float4 bb = *(const float4*)(bias + ct*4);
    bz[0]=bb.x; bz[1]=bb.y; bz[2]=bb.z; bz[3]=bb.w;
  }
  #pragma unroll
  for (int r = 0; r < 8; r++){
    long rr = r0 + rg*8 + r;
    int s = (int)(rr >> 5), b = (int)(rr & 31);      // row = s*32 + b
    float4 o;
    o.x = __builtin_amdgcn_exp2f((acc[r][0]+bz[0]) * scale);
    o.y = __builtin_amdgcn_exp2f((acc[r][1]+bz[1]) * scale);
    o.z = __builtin_amdgcn_exp2f((acc[r][2]+bz[2]) * scale);
    o.w = __builtin_amdgcn_exp2f((acc[r][3]+bz[3]) * scale);
    *(float4*)(outp + ((long)(b * Sn + s)) * An + ct*4) = o;
  }
}

// ---------------- scores + softmax -> weights[q][k][b] f32 (straight to d_out) ----------------
// block: (qt descending, b). 8 queries/block, 256 threads; thread owns key k = ki*256+tid.
// eat/pat hold E=exp2(e'), P=exp2(p'). tanh(x)=1-2/(exp(2x)+1) ->
// score = C - sum_a 2*v_a / (P_a*E_a + 1). Inner loop: fma + rcp + fma.
__global__ __launch_bounds__(256) void score_kernel(const float* __restrict__ eat,
                                                    const float* __restrict__ pat,
                                                    const float* __restrict__ vptr,
                                                    float* __restrict__ wout){
  __shared__ float p[8][256];
  __shared__ float v2[256];
  __shared__ float sc[8][1024];
  int tid = threadIdx.x;
  int qt = gridDim.x - 1 - blockIdx.x;   // big-work tiles first
  int b = blockIdx.y;
  #pragma unroll
  for (int q = 0; q < 8; q++){
    int qg = qt * 8 + q;
    int t = qg > 0 ? qg - 1 : 0;
    p[q][tid] = pat[((long)(b * Sn + t)) * An + tid];   // P = exp2(p')
  }
  float vv = vptr[tid];
  v2[tid] = 2.0f * vv;
  sc[0][tid] = vv;          // block-local reduction for C = sum(v)
  __syncthreads();
  for (int off = 128; off; off >>= 1){
    if (tid < off) sc[0][tid] += sc[0][tid + off];
    __syncthreads();
  }
  float C = sc[0][0];
  __syncthreads();          // everyone has C before sc is reused for scores
  int Lmax = qt * 8 + 6; if (Lmax < 1) Lmax = 1;   // L of the last query in tile
  for (int ki = 0; ki * 256 < Lmax; ki++){
    int k = ki * 256 + tid;
    if (k < Lmax){
      const float4* ep = (const float4*)(eat + ((long)(b * Sn + k)) * An);
      float acc[8] = {0,0,0,0,0,0,0,0};
      for (int c = 0; c < 32; c++){
        float4 ea = ep[2*c], eb = ep[2*c + 1];          // E = exp2(e')
        float e8[8] = {ea.x,ea.y,ea.z,ea.w,eb.x,eb.y,eb.z,eb.w};
        const float4* vp = (const float4*)&v2[c * 8];
        float4 va = vp[0], vb = vp[1];
        float vv8[8] = {va.x,va.y,va.z,va.w,vb.x,vb.y,vb.z,vb.w};
        #pragma unroll
        for (int q = 0; q < 8; q++){
          const float4* pp = (const float4*)&p[q][c * 8];
          float4 p0 = pp[0], p1 = pp[1];
          float pq8[8] = {p0.x,p0.y,p0.z,p0.w,p1.x,p1.y,p1.z,p1.w};
          #pragma unroll
          for (int j = 0; j < 8; j++){
            float t = __builtin_fmaf(pq8[j], e8[j], 1.0f);   // 1 + P*E
            acc[q] += vv8[j] * __builtin_amdgcn_rcpf(t);
          }
        }
      }
      #pragma unroll
      for (int q = 0; q < 8; q++){
        int qg = qt * 8 + q;
        int L = qg - 1; if (L < 1) L = 1;
        sc[q][k] = (k < L) ? (C - acc[q]) : -1e30f;
      }
    }
  }
  __syncthreads();
  // softmax: 32-lane group g handles query row g
  int g = tid >> 5, l = tid & 31;
  float m = -1e30f;
  for (int k = l; k < Lmax; k += 32) m = fmaxf(m, sc[g][k]);
  #pragma unroll
  for (int off = 16; off; off >>= 1) m = fmaxf(m, __shfl_xor(m, off, 32));
  const float LOG2E = 1.4426950408889634f;
  float ssum = 0.0f;
  for (int k = l; k < Lmax; k += 32){
    float e = __builtin_amdgcn_exp2f((sc[g][k] - m) * LOG2E);
    sc[g][k] = e; ssum += e;
  }
  #pragma unroll
  for (int off = 16; off; off >>= 1) ssum += __shfl_xor(ssum, off, 32);
  float rl = 1.0f / ssum;
  int qg = qt * 8 + g;
  // weights out: [q][k][b]; k >= Lmax stays zero from memset; k in [L, Lmax) writes exact 0.
  for (int k = l; k < Lmax; k += 32)
    wout[((long)qg * Sn + k) * Bn + b] = sc[g][k] * rl;
}

// ---------------- context[q][b][e] = sum_k w[q][k][b] * emb[k][b][e] ----------------
__global__ __launch_bounds__(256) void context_kernel(const float* __restrict__ w,
                                                      const float* __restrict__ emb,
                                                      float* __restrict__ ctx){
  __shared__ float xl[8][512];
  __shared__ float wl[8][8];
  int tid = threadIdx.x;
  int qt = gridDim.x - 1 - blockIdx.x;
  int b = blockIdx.y;
  int Lmax = qt * 8 + 6; if (Lmax < 1) Lmax = 1;
  int nch = (Lmax + 7) >> 3;
  float acc[8][2];
  #pragma unroll
  for (int q = 0; q < 8; q++){ acc[q][0] = 0.f; acc[q][1] = 0.f; }
  for (int ch = 0; ch < nch; ch++){
    int k0 = ch * 8;
    __syncthreads();
    if (tid < 64){
      int q = tid >> 3, kk = tid & 7;
      // zeros beyond L[q] guaranteed by memset + exact-0 softmax tail
      wl[q][kk] = w[((long)(qt * 8 + q) * Sn + k0 + kk) * Bn + b];
    }
    #pragma unroll
    for (int i = 0; i < 4; i++){
      int idx = i * 256 + tid;           // 0..1023 over 8 rows x 128 float4
      int kr = idx >> 7, col = (idx & 127) * 4;
      const float4* src = (const float4*)(emb + ((long)((k0 + kr) * Bn + b)) * En);
      *(float4*)&xl[kr][col] = src[idx & 127];
    }
    __syncthreads();
    #pragma unroll
    for (int kk = 0; kk < 8; kk++){
      float x0 = xl[kk][tid], x1 = xl[kk][tid + 256];
      #pragma unroll
      for (int q = 0; q < 8; q++){
        float wv = wl[q][kk];
        acc[q][0] += wv * x0;
        acc[q][1] += wv * x1;
      }
    }
  }
  #pragma unroll
  for (int q = 0; q < 8; q++){
    int qg = qt * 8 + q;
    float* dst = ctx + ((long)(qg * Bn + b)) * En;
    dst[tid]       = acc[q][0];
    dst[tid + 256] = acc[q][1];
  }
}

// ---------------- final v3: LDS-tiled fp32 GEMM, M=64, dbuf, 1 barrier/chunk ----------------
// out[r][h] = outs[r][:].W1[h][:] + ctx[r][:].W2[h][:] + b1[h] + b2[h]
// v2 post-mortem: VALUBusy 40%, ~1 wave/SIMD resident, L2 load latency exposed between
// the two barriers of each BK=8 chunk. v3: 512 threads (8 waves -> 2/SIMD), M=64
// (weight traffic halved, FMA:staging ratio doubled), double-buffered tiles with a
// SINGLE barrier per chunk: iter c issues loads(c+1), computes buf[c&1], writes
// buf[(c+1)&1] (no read/write overlap), then one barrier.
// BN=512 (full width) REQUIRED: ctx aliases outp -> rows must be block-exclusive.
__global__ __launch_bounds__(512) void final_kernel(const float* __restrict__ outsp,
                                                    const float* __restrict__ ctx,
                                                    const float* __restrict__ W1,
                                                    const float* __restrict__ b1,
                                                    const float* __restrict__ W2,
                                                    const float* __restrict__ b2,
                                                    float* __restrict__ outp){
  __shared__ float wl1[2][8][512];  // [buf][k][h]
  __shared__ float wl2[2][8][512];
  __shared__ float xl1[2][8][64];   // [buf][k][row]  (outs)
  __shared__ float xl2[2][8][64];   //                (ctx)
  int tid = threadIdx.x;
  int rg = tid >> 6;                // 0..7 -> rows rg*8..+7
  int ct = tid & 63;                // cols ct*4..+3 and 256+ct*4..+3
  long r0 = (long)blockIdx.x * 64;

  const float* wsrc1 = W1 + (long)tid * 512;   // thread owns W1 row tid, W2 row tid
  const float* wsrc2 = W2 + (long)tid * 512;
  // X staging: threads 0..127 -> outs rows 0..63 (2 k-halves), 128..255 -> ctx
  int xrow = (tid >> 1) & 63, xkg = tid & 1;
  const float* xsrc = (tid < 128) ? (outsp + (r0 + xrow) * 512 + xkg * 4)
                                  : (ctx   + (r0 + xrow) * 512 + xkg * 4);
  float (*xdst)[8][64] = (tid < 128) ? xl1 : xl2;

  float acc[8][8];
  #pragma unroll
  for (int r = 0; r < 8; r++)
    #pragma unroll
    for (int j = 0; j < 8; j++) acc[r][j] = 0.f;

  // preload chunk 0 into buf 0
  float4 a0 = *(const float4*)(wsrc1);
  float4 a1 = *(const float4*)(wsrc1 + 4);
  float4 f0 = *(const float4*)(wsrc2);
  float4 f1 = *(const float4*)(wsrc2 + 4);
  float4 xv;
  if (tid < 256) xv = *(const float4*)(xsrc);
  wl1[0][0][tid]=a0.x; wl1[0][1][tid]=a0.y; wl1[0][2][tid]=a0.z; wl1[0][3][tid]=a0.w;
  wl1[0][4][tid]=a1.x; wl1[0][5][tid]=a1.y; wl1[0][6][tid]=a1.z; wl1[0][7][tid]=a1.w;
  wl2[0][0][tid]=f0.x; wl2[0][1][tid]=f0.y; wl2[0][2][tid]=f0.z; wl2[0][3][tid]=f0.w;
  wl2[0][4][tid]=f1.x; wl2[0][5][tid]=f1.y; wl2[0][6][tid]=f1.z; wl2[0][7][tid]=f1.w;
  if (tid < 256){
    xdst[0][xkg*4+0][xrow]=xv.x; xdst[0][xkg*4+1][xrow]=xv.y;
    xdst[0][xkg*4+2][xrow]=xv.z; xdst[0][xkg*4+3][xrow]=xv.w;
  }
  __syncthreads();

  for (int c = 0; c < 64; c++){
    int cb = c & 1, nb = cb ^ 1;
    if (c < 63){
      a0 = *(const float4*)(wsrc1 + (c+1)*8);
      a1 = *(const float4*)(wsrc1 + (c+1)*8 + 4);
      f0 = *(const float4*)(wsrc2 + (c+1)*8);
      f1 = *(const float4*)(wsrc2 + (c+1)*8 + 4);
      if (tid < 256) xv = *(const float4*)(xsrc + (c+1)*8);
    }
    #pragma unroll
    for (int k = 0; k < 8; k++){
      float4 xa = *(const float4*)&xl1[cb][k][rg*8];     // wave-uniform broadcasts
      float4 xb = *(const float4*)&xl1[cb][k][rg*8+4];
      float4 ya = *(const float4*)&xl2[cb][k][rg*8];
      float4 yb = *(const float4*)&xl2[cb][k][rg*8+4];
      float4 wa = *(const float4*)&wl1[cb][k][ct*4];     // lane-contiguous b128
      float4 wb = *(const float4*)&wl1[cb][k][256+ct*4];
      float4 va = *(const float4*)&wl2[cb][k][ct*4];
      float4 vb = *(const float4*)&wl2[cb][k][256+ct*4];
      float xr8[8] = {xa.x,xa.y,xa.z,xa.w,xb.x,xb.y,xb.z,xb.w};
      float yr8[8] = {ya.x,ya.y,ya.z,ya.w,yb.x,yb.y,yb.z,yb.w};
      float wc8[8] = {wa.x,wa.y,wa.z,wa.w,wb.x,wb.y,wb.z,wb.w};
      float vc8[8] = {va.x,va.y,va.z,va.w,vb.x,vb.y,vb.z,vb.w};
      #pragma unroll
      for (int r = 0; r < 8; r++)
        #pragma unroll
        for (int j = 0; j < 8; j++)
          acc[r][j] += xr8[r]*wc8[j] + yr8[r]*vc8[j];
    }
    if (c < 63){
      wl1[nb][0][tid]=a0.x; wl1[nb][1][tid]=a0.y; wl1[nb][2][tid]=a0.z; wl1[nb][3][tid]=a0.w;
      wl1[nb][4][tid]=a1.x; wl1[nb][5][tid]=a1.y; wl1[nb][6][tid]=a1.z; wl1[nb][7][tid]=a1.w;
      wl2[nb][0][tid]=f0.x; wl2[nb][1][tid]=f0.y; wl2[nb][2][tid]=f0.z; wl2[nb][3][tid]=f0.w;
      wl2[nb][4][tid]=f1.x; wl2[nb][5][tid]=f1.y; wl2[nb][6][tid]=f1.z; wl2[nb][7][tid]=f1.w;
      if (tid < 256){
        xdst[nb][xkg*4+0][xrow]=xv.x; xdst[nb][xkg*4+1][xrow]=xv.y;
        xdst[nb][xkg*4+2][xrow]=xv.z; xdst[nb][xkg*4+3][xrow]=xv.w;
      }
    }
    __syncthreads();
  }

  float bias[8];
  {
    float4 p0 = *(const float4*)(b1 + ct * 4);
    float4 p1 = *(const float4*)(b1 + 256 + ct * 4);
    float4 q0 = *(const float4*)(b2 + ct * 4);
    float4 q1 = *(const float4*)(b2 + 256 + ct * 4);
    bias[0]=p0.x+q0.x; bias[1]=p0.y+q0.y; bias[2]=p0.z+q0.z; bias[3]=p0.w+q0.w;
    bias[4]=p1.x+q1.x; bias[5]=p1.y+q1.y; bias[6]=p1.z+q1.z; bias[7]=p1.w+q1.w;
  }
  // all ctx reads by this block completed before the last barrier; rows are exclusive.
  #pragma unroll
  for (int r = 0; r < 8; r++){
    long row = r0 + rg * 8 + r;
    float4 o0, o1;
    o0.x=acc[r][0]+bias[0]; o0.y=acc[r][1]+bias[1]; o0.z=acc[r][2]+bias[2]; o0.w=acc[r][3]+bias[3];
    o1.x=acc[r][4]+bias[4]; o1.y=acc[r][5]+bias[5]; o1.z=acc[r][6]+bias[6]; o1.w=acc[r][7]+bias[7];
    *(float4*)(outp + row * 512 + ct * 4) = o0;
    *(float4*)(outp + row * 512 + 256 + ct * 4) = o1;
  }
}

extern "C" void kernel_launch(void* const* d_in, const int* in_sizes, int n_in,
                              void* d_out, int out_size, void* d_ws, size_t ws_size,
                              hipStream_t stream) {
  const float* outs  = (const float*)d_in[0];
  const float* emb   = (const float*)d_in[1];
  const float* W_enc = (const float*)d_in[2];
  const float* b_enc = (const float*)d_in[3];
  const float* W_dec = (const float*)d_in[4];
  const float* b_dec = (const float*)d_in[5];
  const float* v     = (const float*)d_in[6];
  const float* W_h2h = (const float*)d_in[7];
  const float* b_h2h = (const float*)d_in[8];
  const float* W_e2h = (const float*)d_in[9];
  const float* b_e2h = (const float*)d_in[10];

  float* out0 = (float*)d_out;                        // (S,B,H) = 16,777,216 f32
  float* outw = out0 + (size_t)Sn * Bn * Hn;          // (S,S,B) = 33,554,432 f32

  // NO d_ws usage. Scratch lives inside d_out's out0 region with phase aliasing:
  //   phase 1: eat [b][k][a] at out0[0..8388608), pat [b][s][a] at out0[8388608..16777216)
  //            (both hold exp2 of the scaled projection)
  //   phase 2 (after score): ctx [q*B+b][E] at out0[0..16777216)
  //   phase 3: final output overwrites out0 (row-exclusive blocks, staged reads, no race)
  float* eat = out0;
  float* pat = out0 + (size_t)8388608;
  float* ctx = out0;

  hipMemsetAsync(outw, 0, (size_t)Sn * Sn * Bn * 4, stream);   // zero masked weights
  proj_kernel<<<512, 512, 0, stream>>>(emb,  W_enc, b_enc, eat);
  proj_kernel<<<512, 512, 0, stream>>>(outs, W_dec, b_dec, pat);
  score_kernel<<<dim3(128, 32), 256, 0, stream>>>(eat, pat, v, outw);
  context_kernel<<<dim3(128, 32), 256, 0, stream>>>(outw, emb, ctx);
  final_kernel<<<512, 512, 0, stream>>>(outs, ctx, W_h2h, b_h2h, W_e2h, b_e2h, out0);
}

// Round 4
// 4359.026 us; speedup vs baseline: 1.0026x; 1.0026x over previous
//
#include <hip/hip_runtime.h>

// S=1024 seq, B=32 batch, H=512 hid, E=512 emb, A=256 att — ALL f32 per reference
#define Sn 1024
#define Bn 32
#define Hn 512
#define En 512
#define An 256

// ---------------- projection v2: out[b][s][a] = exp2( scale*(X[s*B+b][:] . W[a][:] + bias[a]) )
// X: [S*B][512] f32, W: [256][512] f32.
// M=64 rows/block, 512 threads, double-buffered BK=8 LDS tiles, ONE barrier/chunk.
// __launch_bounds__(512,2): VGPR cap 256 — prevents the occupancy-driven cap-128
// accumulator spill seen in round 3's final_kernel.
__global__ __launch_bounds__(512, 2) void proj_kernel(const float* __restrict__ X,
                                                      const float* __restrict__ W,
                                                      const float* __restrict__ bias,
                                                      float* __restrict__ outp){
  __shared__ float wl[2][8][256];   // [buf][k][a-col]
  __shared__ float xl[2][8][64];    // [buf][k][row]
  int tid = threadIdx.x;
  int rg = tid >> 6;                // 0..7 -> rows rg*8..+7
  int ct = tid & 63;                // cols ct*4..+3
  long r0 = (long)blockIdx.x * 64;

  // staging roles: W row = tid>>1 (256 rows x 2 k-halves); X rows by threads 0..127
  int wrow = tid >> 1, wkg = tid & 1;
  const float* wsrc = W + (long)wrow * 512 + wkg * 4;
  int xrow = tid >> 1, xkg = tid & 1;        // valid for tid<128
  const float* xsrc = X + (r0 + xrow) * 512 + xkg * 4;

  float acc[8][4];
  #pragma unroll
  for (int r = 0; r < 8; r++)
    #pragma unroll
    for (int j = 0; j < 4; j++) acc[r][j] = 0.f;

  // preload chunk 0 into buf 0
  float4 wv = *(const float4*)(wsrc);
  float4 xv;
  if (tid < 128) xv = *(const float4*)(xsrc);
  wl[0][wkg*4+0][wrow]=wv.x; wl[0][wkg*4+1][wrow]=wv.y;
  wl[0][wkg*4+2][wrow]=wv.z; wl[0][wkg*4+3][wrow]=wv.w;
  if (tid < 128){
    xl[0][xkg*4+0][xrow]=xv.x; xl[0][xkg*4+1][xrow]=xv.y;
    xl[0][xkg*4+2][xrow]=xv.z; xl[0][xkg*4+3][xrow]=xv.w;
  }
  __syncthreads();

  for (int c = 0; c < 64; c++){
    int cb = c & 1, nb = cb ^ 1;
    if (c < 63){
      wv = *(const float4*)(wsrc + (c+1)*8);
      if (tid < 128) xv = *(const float4*)(xsrc + (c+1)*8);
    }
    #pragma unroll
    for (int k = 0; k < 8; k++){
      float4 xa = *(const float4*)&xl[cb][k][rg*8];      // wave-uniform broadcast
      float4 xb = *(const float4*)&xl[cb][k][rg*8+4];
      float4 wc = *(const float4*)&wl[cb][k][ct*4];      // lane-contiguous b128
      float xr8[8] = {xa.x,xa.y,xa.z,xa.w,xb.x,xb.y,xb.z,xb.w};
      float wc4[4] = {wc.x,wc.y,wc.z,wc.w};
      #pragma unroll
      for (int r = 0; r < 8; r++)
        #pragma unroll
        for (int j = 0; j < 4; j++)
          acc[r][j] += xr8[r]*wc4[j];
    }
    if (c < 63){
      wl[nb][wkg*4+0][wrow]=wv.x; wl[nb][wkg*4+1][wrow]=wv.y;
      wl[nb][wkg*4+2][wrow]=wv.z; wl[nb][wkg*4+3][wrow]=wv.w;
      if (tid < 128){
        xl[nb][xkg*4+0][xrow]=xv.x; xl[nb][xkg*4+1][xrow]=xv.y;
        xl[nb][xkg*4+2][xrow]=xv.z; xl[nb][xkg*4+3][xrow]=xv.w;
      }
    }
    __syncthreads();
  }

  const float scale = 2.8853900817779268f;  // 2*log2(e): arg pre-scale for exp2-based tanh
  float bz[4];
  {
    float4 bb = *(const float4*)(bias + ct*4);
    bz[0]=bb.x; bz[1]=bb.y; bz[2]=bb.z; bz[3]=bb.w;
  }
  #pragma unroll
  for (int r = 0; r < 8; r++){
    long rr = r0 + rg*8 + r;
    int s = (int)(rr >> 5), b = (int)(rr & 31);      // row = s*32 + b
    float4 o;
    o.x = __builtin_amdgcn_exp2f((acc[r][0]+bz[0]) * scale);
    o.y = __builtin_amdgcn_exp2f((acc[r][1]+bz[1]) * scale);
    o.z = __builtin_amdgcn_exp2f((acc[r][2]+bz[2]) * scale);
    o.w = __builtin_amdgcn_exp2f((acc[r][3]+bz[3]) * scale);
    *(float4*)(outp + ((long)(b * Sn + s)) * An + ct*4) = o;
  }
}

// ---------------- scores + softmax -> weights[q][k][b] f32 (straight to d_out) ----------------
// block: (qt descending, b). 8 queries/block, 256 threads; thread owns key k = ki*256+tid.
// eat/pat hold E=exp2(e'), P=exp2(p'). tanh(x)=1-2/(exp(2x)+1) ->
// score = C - sum_a 2*v_a / (P_a*E_a + 1). Inner loop: fma + rcp + fma.
__global__ __launch_bounds__(256) void score_kernel(const float* __restrict__ eat,
                                                    const float* __restrict__ pat,
                                                    const float* __restrict__ vptr,
                                                    float* __restrict__ wout){
  __shared__ float p[8][256];
  __shared__ float v2[256];
  __shared__ float sc[8][1024];
  int tid = threadIdx.x;
  int qt = gridDim.x - 1 - blockIdx.x;   // big-work tiles first
  int b = blockIdx.y;
  #pragma unroll
  for (int q = 0; q < 8; q++){
    int qg = qt * 8 + q;
    int t = qg > 0 ? qg - 1 : 0;
    p[q][tid] = pat[((long)(b * Sn + t)) * An + tid];   // P = exp2(p')
  }
  float vv = vptr[tid];
  v2[tid] = 2.0f * vv;
  sc[0][tid] = vv;          // block-local reduction for C = sum(v)
  __syncthreads();
  for (int off = 128; off; off >>= 1){
    if (tid < off) sc[0][tid] += sc[0][tid + off];
    __syncthreads();
  }
  float C = sc[0][0];
  __syncthreads();          // everyone has C before sc is reused for scores
  int Lmax = qt * 8 + 6; if (Lmax < 1) Lmax = 1;   // L of the last query in tile
  for (int ki = 0; ki * 256 < Lmax; ki++){
    int k = ki * 256 + tid;
    if (k < Lmax){
      const float4* ep = (const float4*)(eat + ((long)(b * Sn + k)) * An);
      float acc[8] = {0,0,0,0,0,0,0,0};
      for (int c = 0; c < 32; c++){
        float4 ea = ep[2*c], eb = ep[2*c + 1];          // E = exp2(e')
        float e8[8] = {ea.x,ea.y,ea.z,ea.w,eb.x,eb.y,eb.z,eb.w};
        const float4* vp = (const float4*)&v2[c * 8];
        float4 va = vp[0], vb = vp[1];
        float vv8[8] = {va.x,va.y,va.z,va.w,vb.x,vb.y,vb.z,vb.w};
        #pragma unroll
        for (int q = 0; q < 8; q++){
          const float4* pp = (const float4*)&p[q][c * 8];
          float4 p0 = pp[0], p1 = pp[1];
          float pq8[8] = {p0.x,p0.y,p0.z,p0.w,p1.x,p1.y,p1.z,p1.w};
          #pragma unroll
          for (int j = 0; j < 8; j++){
            float t = __builtin_fmaf(pq8[j], e8[j], 1.0f);   // 1 + P*E
            acc[q] += vv8[j] * __builtin_amdgcn_rcpf(t);
          }
        }
      }
      #pragma unroll
      for (int q = 0; q < 8; q++){
        int qg = qt * 8 + q;
        int L = qg - 1; if (L < 1) L = 1;
        sc[q][k] = (k < L) ? (C - acc[q]) : -1e30f;
      }
    }
  }
  __syncthreads();
  // softmax: 32-lane group g handles query row g
  int g = tid >> 5, l = tid & 31;
  float m = -1e30f;
  for (int k = l; k < Lmax; k += 32) m = fmaxf(m, sc[g][k]);
  #pragma unroll
  for (int off = 16; off; off >>= 1) m = fmaxf(m, __shfl_xor(m, off, 32));
  const float LOG2E = 1.4426950408889634f;
  float ssum = 0.0f;
  for (int k = l; k < Lmax; k += 32){
    float e = __builtin_amdgcn_exp2f((sc[g][k] - m) * LOG2E);
    sc[g][k] = e; ssum += e;
  }
  #pragma unroll
  for (int off = 16; off; off >>= 1) ssum += __shfl_xor(ssum, off, 32);
  float rl = 1.0f / ssum;
  int qg = qt * 8 + g;
  // weights out: [q][k][b]; k >= Lmax stays zero from memset; k in [L, Lmax) writes exact 0.
  for (int k = l; k < Lmax; k += 32)
    wout[((long)qg * Sn + k) * Bn + b] = sc[g][k] * rl;
}

// ---------------- context[q][b][e] = sum_k w[q][k][b] * emb[k][b][e] ----------------
__global__ __launch_bounds__(256) void context_kernel(const float* __restrict__ w,
                                                      const float* __restrict__ emb,
                                                      float* __restrict__ ctx){
  __shared__ float xl[8][512];
  __shared__ float wl[8][8];
  int tid = threadIdx.x;
  int qt = gridDim.x - 1 - blockIdx.x;
  int b = blockIdx.y;
  int Lmax = qt * 8 + 6; if (Lmax < 1) Lmax = 1;
  int nch = (Lmax + 7) >> 3;
  float acc[8][2];
  #pragma unroll
  for (int q = 0; q < 8; q++){ acc[q][0] = 0.f; acc[q][1] = 0.f; }
  for (int ch = 0; ch < nch; ch++){
    int k0 = ch * 8;
    __syncthreads();
    if (tid < 64){
      int q = tid >> 3, kk = tid & 7;
      // zeros beyond L[q] guaranteed by memset + exact-0 softmax tail
      wl[q][kk] = w[((long)(qt * 8 + q) * Sn + k0 + kk) * Bn + b];
    }
    #pragma unroll
    for (int i = 0; i < 4; i++){
      int idx = i * 256 + tid;           // 0..1023 over 8 rows x 128 float4
      int kr = idx >> 7, col = (idx & 127) * 4;
      const float4* src = (const float4*)(emb + ((long)((k0 + kr) * Bn + b)) * En);
      *(float4*)&xl[kr][col] = src[idx & 127];
    }
    __syncthreads();
    #pragma unroll
    for (int kk = 0; kk < 8; kk++){
      float x0 = xl[kk][tid], x1 = xl[kk][tid + 256];
      #pragma unroll
      for (int q = 0; q < 8; q++){
        float wv = wl[q][kk];
        acc[q][0] += wv * x0;
        acc[q][1] += wv * x1;
      }
    }
  }
  #pragma unroll
  for (int q = 0; q < 8; q++){
    int qg = qt * 8 + q;
    float* dst = ctx + ((long)(qg * Bn + b)) * En;
    dst[tid]       = acc[q][0];
    dst[tid + 256] = acc[q][1];
  }
}

// ---------------- final v4: LDS-tiled fp32 GEMM, M=64, dbuf, 1 barrier/chunk ----------------
// out[r][h] = outs[r][:].W1[h][:] + ctx[r][:].W2[h][:] + b1[h] + b2[h]
// Round-3 post-mortem: __launch_bounds__(512) let the compiler target 2 blocks/CU
// (4 waves/SIMD -> VGPR cap 128); live set ~160 -> acc spilled to scratch in the
// K-loop -> 10GB HBM traffic, 2765us. v4: __launch_bounds__(512, 2) = 2 waves/EU
// min (1 block/CU) -> VGPR cap 256, no spill. Schedule unchanged: 8 waves,
// double-buffered tiles, single barrier per BK=8 chunk (loads(c+1) issued before
// compute(c), ds_write to the other buffer, one barrier).
// BN=512 (full width) REQUIRED: ctx aliases outp -> rows must be block-exclusive.
__global__ __launch_bounds__(512, 2) void final_kernel(const float* __restrict__ outsp,
                                                       const float* __restrict__ ctx,
                                                       const float* __restrict__ W1,
                                                       const float* __restrict__ b1,
                                                       const float* __restrict__ W2,
                                                       const float* __restrict__ b2,
                                                       float* __restrict__ outp){
  __shared__ float wl1[2][8][512];  // [buf][k][h]
  __shared__ float wl2[2][8][512];
  __shared__ float xl1[2][8][64];   // [buf][k][row]  (outs)
  __shared__ float xl2[2][8][64];   //                (ctx)
  int tid = threadIdx.x;
  int rg = tid >> 6;                // 0..7 -> rows rg*8..+7
  int ct = tid & 63;                // cols ct*4..+3 and 256+ct*4..+3
  long r0 = (long)blockIdx.x * 64;

  const float* wsrc1 = W1 + (long)tid * 512;   // thread owns W1 row tid, W2 row tid
  const float* wsrc2 = W2 + (long)tid * 512;
  // X staging: threads 0..127 -> outs rows 0..63 (2 k-halves), 128..255 -> ctx
  int xrow = (tid >> 1) & 63, xkg = tid & 1;
  const float* xsrc = (tid < 128) ? (outsp + (r0 + xrow) * 512 + xkg * 4)
                                  : (ctx   + (r0 + xrow) * 512 + xkg * 4);
  float (*xdst)[8][64] = (tid < 128) ? xl1 : xl2;

  float acc[8][8];
  #pragma unroll
  for (int r = 0; r < 8; r++)
    #pragma unroll
    for (int j = 0; j < 8; j++) acc[r][j] = 0.f;

  // preload chunk 0 into buf 0
  float4 a0 = *(const float4*)(wsrc1);
  float4 a1 = *(const float4*)(wsrc1 + 4);
  float4 f0 = *(const float4*)(wsrc2);
  float4 f1 = *(const float4*)(wsrc2 + 4);
  float4 xv;
  if (tid < 256) xv = *(const float4*)(xsrc);
  wl1[0][0][tid]=a0.x; wl1[0][1][tid]=a0.y; wl1[0][2][tid]=a0.z; wl1[0][3][tid]=a0.w;
  wl1[0][4][tid]=a1.x; wl1[0][5][tid]=a1.y; wl1[0][6][tid]=a1.z; wl1[0][7][tid]=a1.w;
  wl2[0][0][tid]=f0.x; wl2[0][1][tid]=f0.y; wl2[0][2][tid]=f0.z; wl2[0][3][tid]=f0.w;
  wl2[0][4][tid]=f1.x; wl2[0][5][tid]=f1.y; wl2[0][6][tid]=f1.z; wl2[0][7][tid]=f1.w;
  if (tid < 256){
    xdst[0][xkg*4+0][xrow]=xv.x; xdst[0][xkg*4+1][xrow]=xv.y;
    xdst[0][xkg*4+2][xrow]=xv.z; xdst[0][xkg*4+3][xrow]=xv.w;
  }
  __syncthreads();

  for (int c = 0; c < 64; c++){
    int cb = c & 1, nb = cb ^ 1;
    if (c < 63){
      a0 = *(const float4*)(wsrc1 + (c+1)*8);
      a1 = *(const float4*)(wsrc1 + (c+1)*8 + 4);
      f0 = *(const float4*)(wsrc2 + (c+1)*8);
      f1 = *(const float4*)(wsrc2 + (c+1)*8 + 4);
      if (tid < 256) xv = *(const float4*)(xsrc + (c+1)*8);
    }
    #pragma unroll
    for (int k = 0; k < 8; k++){
      float4 xa = *(const float4*)&xl1[cb][k][rg*8];     // wave-uniform broadcasts
      float4 xb = *(const float4*)&xl1[cb][k][rg*8+4];
      float4 ya = *(const float4*)&xl2[cb][k][rg*8];
      float4 yb = *(const float4*)&xl2[cb][k][rg*8+4];
      float4 wa = *(const float4*)&wl1[cb][k][ct*4];     // lane-contiguous b128
      float4 wb = *(const float4*)&wl1[cb][k][256+ct*4];
      float4 va = *(const float4*)&wl2[cb][k][ct*4];
      float4 vb = *(const float4*)&wl2[cb][k][256+ct*4];
      float xr8[8] = {xa.x,xa.y,xa.z,xa.w,xb.x,xb.y,xb.z,xb.w};
      float yr8[8] = {ya.x,ya.y,ya.z,ya.w,yb.x,yb.y,yb.z,yb.w};
      float wc8[8] = {wa.x,wa.y,wa.z,wa.w,wb.x,wb.y,wb.z,wb.w};
      float vc8[8] = {va.x,va.y,va.z,va.w,vb.x,vb.y,vb.z,vb.w};
      #pragma unroll
      for (int r = 0; r < 8; r++)
        #pragma unroll
        for (int j = 0; j < 8; j++)
          acc[r][j] += xr8[r]*wc8[j] + yr8[r]*vc8[j];
    }
    if (c < 63){
      wl1[nb][0][tid]=a0.x; wl1[nb][1][tid]=a0.y; wl1[nb][2][tid]=a0.z; wl1[nb][3][tid]=a0.w;
      wl1[nb][4][tid]=a1.x; wl1[nb][5][tid]=a1.y; wl1[nb][6][tid]=a1.z; wl1[nb][7][tid]=a1.w;
      wl2[nb][0][tid]=f0.x; wl2[nb][1][tid]=f0.y; wl2[nb][2][tid]=f0.z; wl2[nb][3][tid]=f0.w;
      wl2[nb][4][tid]=f1.x; wl2[nb][5][tid]=f1.y; wl2[nb][6][tid]=f1.z; wl2[nb][7][tid]=f1.w;
      if (tid < 256){
        xdst[nb][xkg*4+0][xrow]=xv.x; xdst[nb][xkg*4+1][xrow]=xv.y;
        xdst[nb][xkg*4+2][xrow]=xv.z; xdst[nb][xkg*4+3][xrow]=xv.w;
      }
    }
    __syncthreads();
  }

  float bias[8];
  {
    float4 p0 = *(const float4*)(b1 + ct * 4);
    float4 p1 = *(const float4*)(b1 + 256 + ct * 4);
    float4 q0 = *(const float4*)(b2 + ct * 4);
    float4 q1 = *(const float4*)(b2 + 256 + ct * 4);
    bias[0]=p0.x+q0.x; bias[1]=p0.y+q0.y; bias[2]=p0.z+q0.z; bias[3]=p0.w+q0.w;
    bias[4]=p1.x+q1.x; bias[5]=p1.y+q1.y; bias[6]=p1.z+q1.z; bias[7]=p1.w+q1.w;
  }
  // all ctx reads by this block completed before the last barrier; rows are exclusive.
  #pragma unroll
  for (int r = 0; r < 8; r++){
    long row = r0 + rg * 8 + r;
    float4 o0, o1;
    o0.x=acc[r][0]+bias[0]; o0.y=acc[r][1]+bias[1]; o0.z=acc[r][2]+bias[2]; o0.w=acc[r][3]+bias[3];
    o1.x=acc[r][4]+bias[4]; o1.y=acc[r][5]+bias[5]; o1.z=acc[r][6]+bias[6]; o1.w=acc[r][7]+bias[7];
    *(float4*)(outp + row * 512 + ct * 4) = o0;
    *(float4*)(outp + row * 512 + 256 + ct * 4) = o1;
  }
}

extern "C" void kernel_launch(void* const* d_in, const int* in_sizes, int n_in,
                              void* d_out, int out_size, void* d_ws, size_t ws_size,
                              hipStream_t stream) {
  const float* outs  = (const float*)d_in[0];
  const float* emb   = (const float*)d_in[1];
  const float* W_enc = (const float*)d_in[2];
  const float* b_enc = (const float*)d_in[3];
  const float* W_dec = (const float*)d_in[4];
  const float* b_dec = (const float*)d_in[5];
  const float* v     = (const float*)d_in[6];
  const float* W_h2h = (const float*)d_in[7];
  const float* b_h2h = (const float*)d_in[8];
  const float* W_e2h = (const float*)d_in[9];
  const float* b_e2h = (const float*)d_in[10];

  float* out0 = (float*)d_out;                        // (S,B,H) = 16,777,216 f32
  float* outw = out0 + (size_t)Sn * Bn * Hn;          // (S,S,B) = 33,554,432 f32

  // NO d_ws usage. Scratch lives inside d_out's out0 region with phase aliasing:
  //   phase 1: eat [b][k][a] at out0[0..8388608), pat [b][s][a] at out0[8388608..16777216)
  //            (both hold exp2 of the scaled projection)
  //   phase 2 (after score): ctx [q*B+b][E] at out0[0..16777216)
  //   phase 3: final output overwrites out0 (row-exclusive blocks, staged reads, no race)
  float* eat = out0;
  float* pat = out0 + (size_t)8388608;
  float* ctx = out0;

  hipMemsetAsync(outw, 0, (size_t)Sn * Sn * Bn * 4, stream);   // zero masked weights
  proj_kernel<<<512, 512, 0, stream>>>(emb,  W_enc, b_enc, eat);
  proj_kernel<<<512, 512, 0, stream>>>(outs, W_dec, b_dec, pat);
  score_kernel<<<dim3(128, 32), 256, 0, stream>>>(eat, pat, v, outw);
  context_kernel<<<dim3(128, 32), 256, 0, stream>>>(outw, emb, ctx);
  final_kernel<<<512, 512, 0, stream>>>(outs, ctx, W_h2h, b_h2h, W_e2h, b_e2h, out0);
}

// Round 7
// 2336.219 us; speedup vs baseline: 1.8707x; 1.8658x over previous
//
#include <hip/hip_runtime.h>

// S=1024 seq, B=32 batch, H=512 hid, E=512 emb, A=256 att — ALL f32 per reference
#define Sn 1024
#define Bn 32
#define Hn 512
#define En 512
#define An 256

// ---------------- projection: out[b][s][a] = exp2( scale*(X[s*B+b][:] . W[a][:] + bias[a]) )
// X: [S*B][512] f32, W: [256][512] f32.
// M=64 rows/block, 512 threads, double-buffered BK=8 LDS tiles, ONE barrier/chunk.
// Live set ~60 regs — fits the 128-reg budget the backend picks for 512-thr blocks.
__global__ __launch_bounds__(512) void proj_kernel(const float* __restrict__ X,
                                                   const float* __restrict__ W,
                                                   const float* __restrict__ bias,
                                                   float* __restrict__ outp){
  __shared__ float wl[2][8][256];   // [buf][k][a-col]
  __shared__ float xl[2][8][64];    // [buf][k][row]
  int tid = threadIdx.x;
  int rg = tid >> 6;                // 0..7 -> rows rg*8..+7
  int ct = tid & 63;                // cols ct*4..+3
  long r0 = (long)blockIdx.x * 64;

  // staging roles: W row = tid>>1 (256 rows x 2 k-halves); X rows by threads 0..127
  int wrow = tid >> 1, wkg = tid & 1;
  const float* wsrc = W + (long)wrow * 512 + wkg * 4;
  int xrow = tid >> 1, xkg = tid & 1;        // valid for tid<128
  const float* xsrc = X + (r0 + xrow) * 512 + xkg * 4;

  float acc[8][4];
  #pragma unroll
  for (int r = 0; r < 8; r++)
    #pragma unroll
    for (int j = 0; j < 4; j++) acc[r][j] = 0.f;

  // preload chunk 0 into buf 0
  float4 wv = *(const float4*)(wsrc);
  float4 xv;
  if (tid < 128) xv = *(const float4*)(xsrc);
  wl[0][wkg*4+0][wrow]=wv.x; wl[0][wkg*4+1][wrow]=wv.y;
  wl[0][wkg*4+2][wrow]=wv.z; wl[0][wkg*4+3][wrow]=wv.w;
  if (tid < 128){
    xl[0][xkg*4+0][xrow]=xv.x; xl[0][xkg*4+1][xrow]=xv.y;
    xl[0][xkg*4+2][xrow]=xv.z; xl[0][xkg*4+3][xrow]=xv.w;
  }
  __syncthreads();

  for (int c = 0; c < 64; c++){
    int cb = c & 1, nb = cb ^ 1;
    if (c < 63){
      wv = *(const float4*)(wsrc + (c+1)*8);
      if (tid < 128) xv = *(const float4*)(xsrc + (c+1)*8);
    }
    #pragma unroll
    for (int k = 0; k < 8; k++){
      float4 xa = *(const float4*)&xl[cb][k][rg*8];      // wave-uniform broadcast
      float4 xb = *(const float4*)&xl[cb][k][rg*8+4];
      float4 wc = *(const float4*)&wl[cb][k][ct*4];      // lane-contiguous b128
      float xr8[8] = {xa.x,xa.y,xa.z,xa.w,xb.x,xb.y,xb.z,xb.w};
      float wc4[4] = {wc.x,wc.y,wc.z,wc.w};
      #pragma unroll
      for (int r = 0; r < 8; r++)
        #pragma unroll
        for (int j = 0; j < 4; j++)
          acc[r][j] += xr8[r]*wc4[j];
    }
    if (c < 63){
      wl[nb][wkg*4+0][wrow]=wv.x; wl[nb][wkg*4+1][wrow]=wv.y;
      wl[nb][wkg*4+2][wrow]=wv.z; wl[nb][wkg*4+3][wrow]=wv.w;
      if (tid < 128){
        xl[nb][xkg*4+0][xrow]=xv.x; xl[nb][xkg*4+1][xrow]=xv.y;
        xl[nb][xkg*4+2][xrow]=xv.z; xl[nb][xkg*4+3][xrow]=xv.w;
      }
    }
    __syncthreads();
  }

  const float scale = 2.8853900817779268f;  // 2*log2(e): arg pre-scale for exp2-based tanh
  float bz[4];
  {
    float4 bb = *(const float4*)(bias + ct*4);
    bz[0]=bb.x; bz[1]=bb.y; bz[2]=bb.z; bz[3]=bb.w;
  }
  #pragma unroll
  for (int r = 0; r < 8; r++){
    long rr = r0 + rg*8 + r;
    int s = (int)(rr >> 5), b = (int)(rr & 31);      // row = s*32 + b
    float4 o;
    o.x = __builtin_amdgcn_exp2f((acc[r][0]+bz[0]) * scale);
    o.y = __builtin_amdgcn_exp2f((acc[r][1]+bz[1]) * scale);
    o.z = __builtin_amdgcn_exp2f((acc[r][2]+bz[2]) * scale);
    o.w = __builtin_amdgcn_exp2f((acc[r][3]+bz[3]) * scale);
    *(float4*)(outp + ((long)(b * Sn + s)) * An + ct*4) = o;
  }
}

// ---------------- scores + softmax -> weights[q][k][b] f32 (straight to d_out) ----------------
// block: (qt descending, b). 8 queries/block, 256 threads; thread owns key k = ki*256+tid.
// eat/pat hold E=exp2(e'), P=exp2(p'). tanh(x)=1-2/(exp(2x)+1) ->
// score = C - sum_a 2*v_a / (P_a*E_a + 1). Inner loop: fma + rcp + fma.
__global__ __launch_bounds__(256) void score_kernel(const float* __restrict__ eat,
                                                    const float* __restrict__ pat,
                                                    const float* __restrict__ vptr,
                                                    float* __restrict__ wout){
  __shared__ float p[8][256];
  __shared__ float v2[256];
  __shared__ float sc[8][1024];
  int tid = threadIdx.x;
  int qt = gridDim.x - 1 - blockIdx.x;   // big-work tiles first
  int b = blockIdx.y;
  #pragma unroll
  for (int q = 0; q < 8; q++){
    int qg = qt * 8 + q;
    int t = qg > 0 ? qg - 1 : 0;
    p[q][tid] = pat[((long)(b * Sn + t)) * An + tid];   // P = exp2(p')
  }
  float vv = vptr[tid];
  v2[tid] = 2.0f * vv;
  sc[0][tid] = vv;          // block-local reduction for C = sum(v)
  __syncthreads();
  for (int off = 128; off; off >>= 1){
    if (tid < off) sc[0][tid] += sc[0][tid + off];
    __syncthreads();
  }
  float C = sc[0][0];
  __syncthreads();          // everyone has C before sc is reused for scores
  int Lmax = qt * 8 + 6; if (Lmax < 1) Lmax = 1;   // L of the last query in tile
  for (int ki = 0; ki * 256 < Lmax; ki++){
    int k = ki * 256 + tid;
    if (k < Lmax){
      const float4* ep = (const float4*)(eat + ((long)(b * Sn + k)) * An);
      float acc[8] = {0,0,0,0,0,0,0,0};
      for (int c = 0; c < 32; c++){
        float4 ea = ep[2*c], eb = ep[2*c + 1];          // E = exp2(e')
        float e8[8] = {ea.x,ea.y,ea.z,ea.w,eb.x,eb.y,eb.z,eb.w};
        const float4* vp = (const float4*)&v2[c * 8];
        float4 va = vp[0], vb = vp[1];
        float vv8[8] = {va.x,va.y,va.z,va.w,vb.x,vb.y,vb.z,vb.w};
        #pragma unroll
        for (int q = 0; q < 8; q++){
          const float4* pp = (const float4*)&p[q][c * 8];
          float4 p0 = pp[0], p1 = pp[1];
          float pq8[8] = {p0.x,p0.y,p0.z,p0.w,p1.x,p1.y,p1.z,p1.w};
          #pragma unroll
          for (int j = 0; j < 8; j++){
            float t = __builtin_fmaf(pq8[j], e8[j], 1.0f);   // 1 + P*E
            acc[q] += vv8[j] * __builtin_amdgcn_rcpf(t);
          }
        }
      }
      #pragma unroll
      for (int q = 0; q < 8; q++){
        int qg = qt * 8 + q;
        int L = qg - 1; if (L < 1) L = 1;
        sc[q][k] = (k < L) ? (C - acc[q]) : -1e30f;
      }
    }
  }
  __syncthreads();
  // softmax: 32-lane group g handles query row g
  int g = tid >> 5, l = tid & 31;
  float m = -1e30f;
  for (int k = l; k < Lmax; k += 32) m = fmaxf(m, sc[g][k]);
  #pragma unroll
  for (int off = 16; off; off >>= 1) m = fmaxf(m, __shfl_xor(m, off, 32));
  const float LOG2E = 1.4426950408889634f;
  float ssum = 0.0f;
  for (int k = l; k < Lmax; k += 32){
    float e = __builtin_amdgcn_exp2f((sc[g][k] - m) * LOG2E);
    sc[g][k] = e; ssum += e;
  }
  #pragma unroll
  for (int off = 16; off; off >>= 1) ssum += __shfl_xor(ssum, off, 32);
  float rl = 1.0f / ssum;
  int qg = qt * 8 + g;
  // weights out: [q][k][b]; k >= Lmax stays zero from memset; k in [L, Lmax) writes exact 0.
  for (int k = l; k < Lmax; k += 32)
    wout[((long)qg * Sn + k) * Bn + b] = sc[g][k] * rl;
}

// ---------------- context[q][b][e] = sum_k w[q][k][b] * emb[k][b][e] ----------------
__global__ __launch_bounds__(256) void context_kernel(const float* __restrict__ w,
                                                      const float* __restrict__ emb,
                                                      float* __restrict__ ctx){
  __shared__ float xl[8][512];
  __shared__ float wl[8][8];
  int tid = threadIdx.x;
  int qt = gridDim.x - 1 - blockIdx.x;
  int b = blockIdx.y;
  int Lmax = qt * 8 + 6; if (Lmax < 1) Lmax = 1;
  int nch = (Lmax + 7) >> 3;
  float acc[8][2];
  #pragma unroll
  for (int q = 0; q < 8; q++){ acc[q][0] = 0.f; acc[q][1] = 0.f; }
  for (int ch = 0; ch < nch; ch++){
    int k0 = ch * 8;
    __syncthreads();
    if (tid < 64){
      int q = tid >> 3, kk = tid & 7;
      // zeros beyond L[q] guaranteed by memset + exact-0 softmax tail
      wl[q][kk] = w[((long)(qt * 8 + q) * Sn + k0 + kk) * Bn + b];
    }
    #pragma unroll
    for (int i = 0; i < 4; i++){
      int idx = i * 256 + tid;           // 0..1023 over 8 rows x 128 float4
      int kr = idx >> 7, col = (idx & 127) * 4;
      const float4* src = (const float4*)(emb + ((long)((k0 + kr) * Bn + b)) * En);
      *(float4*)&xl[kr][col] = src[idx & 127];
    }
    __syncthreads();
    #pragma unroll
    for (int kk = 0; kk < 8; kk++){
      float x0 = xl[kk][tid], x1 = xl[kk][tid + 256];
      #pragma unroll
      for (int q = 0; q < 8; q++){
        float wv = wl[q][kk];
        acc[q][0] += wv * x0;
        acc[q][1] += wv * x1;
      }
    }
  }
  #pragma unroll
  for (int q = 0; q < 8; q++){
    int qg = qt * 8 + q;
    float* dst = ctx + ((long)(qg * Bn + b)) * En;
    dst[tid]       = acc[q][0];
    dst[tid + 256] = acc[q][1];
  }
}

// ---------------- final v5: LDS-tiled fp32 GEMM, M=32, 512 thr, dbuf, 1 barrier/chunk ----
// out[r][h] = outs[r][:].W1[h][:] + ctx[r][:].W2[h][:] + b1[h] + b2[h]
// Round-3/4 post-mortem: backend budgets 128 VGPR for 512-thr blocks (4 waves/EU
// heuristic); launch_bounds' 2nd arg is an occupancy FLOOR (register ceiling) and
// cannot raise the budget. M=64's live set (~150: 64 acc + 20 prefetch + LDS temps)
// spilled accumulators in-loop -> 10GB scratch traffic. v5 keeps the v3 schedule
// (8 waves, dbuf, loads(c+1) before compute(c), one barrier per BK=8 chunk) but
// M=32 -> acc[4][8]=32 regs, live set ~90 < 128: no spill. LDS 68KB -> 2 blocks/CU
// co-resident (4 waves/SIMD TLP). Weight L2 streaming: 1024 blocks x 2MB = 2GB
// (~58us of L2 BW, hidden under FMAs; per-k FMA:LDS ratio 64:6).
// BN=512 (full width) REQUIRED: ctx aliases outp -> rows must be block-exclusive.
__global__ __launch_bounds__(512) void final_kernel(const float* __restrict__ outsp,
                                                    const float* __restrict__ ctx,
                                                    const float* __restrict__ W1,
                                                    const float* __restrict__ b1,
                                                    const float* __restrict__ W2,
                                                    const float* __restrict__ b2,
                                                    float* __restrict__ outp){
  __shared__ float wl1[2][8][512];  // [buf][k][h]
  __shared__ float wl2[2][8][512];
  __shared__ float xl1[2][8][32];   // [buf][k][row]  (outs)
  __shared__ float xl2[2][8][32];   //                (ctx)
  int tid = threadIdx.x;
  int rg = tid >> 6;                // 0..7 -> rows rg*4..+3
  int ct = tid & 63;                // cols ct*4..+3 and 256+ct*4..+3
  long r0 = (long)blockIdx.x * 32;

  const float* wsrc1 = W1 + (long)tid * 512;   // thread owns W1 row tid, W2 row tid
  const float* wsrc2 = W2 + (long)tid * 512;
  // X staging: threads 0..63 -> outs rows 0..31 (2 k-halves), 64..127 -> ctx
  int xrow = (tid >> 1) & 31, xkg = tid & 1;
  const float* xsrc = (tid < 64) ? (outsp + (r0 + xrow) * 512 + xkg * 4)
                                 : (ctx   + (r0 + xrow) * 512 + xkg * 4);
  float (*xdst)[8][32] = (tid < 64) ? xl1 : xl2;

  float acc[4][8];
  #pragma unroll
  for (int r = 0; r < 4; r++)
    #pragma unroll
    for (int j = 0; j < 8; j++) acc[r][j] = 0.f;

  // preload chunk 0 into buf 0
  float4 a0 = *(const float4*)(wsrc1);
  float4 a1 = *(const float4*)(wsrc1 + 4);
  float4 f0 = *(const float4*)(wsrc2);
  float4 f1 = *(const float4*)(wsrc2 + 4);
  float4 xv;
  if (tid < 128) xv = *(const float4*)(xsrc);
  wl1[0][0][tid]=a0.x; wl1[0][1][tid]=a0.y; wl1[0][2][tid]=a0.z; wl1[0][3][tid]=a0.w;
  wl1[0][4][tid]=a1.x; wl1[0][5][tid]=a1.y; wl1[0][6][tid]=a1.z; wl1[0][7][tid]=a1.w;
  wl2[0][0][tid]=f0.x; wl2[0][1][tid]=f0.y; wl2[0][2][tid]=f0.z; wl2[0][3][tid]=f0.w;
  wl2[0][4][tid]=f1.x; wl2[0][5][tid]=f1.y; wl2[0][6][tid]=f1.z; wl2[0][7][tid]=f1.w;
  if (tid < 128){
    xdst[0][xkg*4+0][xrow]=xv.x; xdst[0][xkg*4+1][xrow]=xv.y;
    xdst[0][xkg*4+2][xrow]=xv.z; xdst[0][xkg*4+3][xrow]=xv.w;
  }
  __syncthreads();

  for (int c = 0; c < 64; c++){
    int cb = c & 1, nb = cb ^ 1;
    if (c < 63){
      a0 = *(const float4*)(wsrc1 + (c+1)*8);
      a1 = *(const float4*)(wsrc1 + (c+1)*8 + 4);
      f0 = *(const float4*)(wsrc2 + (c+1)*8);
      f1 = *(const float4*)(wsrc2 + (c+1)*8 + 4);
      if (tid < 128) xv = *(const float4*)(xsrc + (c+1)*8);
    }
    #pragma unroll
    for (int k = 0; k < 8; k++){
      float4 xa = *(const float4*)&xl1[cb][k][rg*4];     // wave-uniform broadcasts
      float4 ya = *(const float4*)&xl2[cb][k][rg*4];
      float4 wa = *(const float4*)&wl1[cb][k][ct*4];     // lane-contiguous b128
      float4 wb = *(const float4*)&wl1[cb][k][256+ct*4];
      float4 va = *(const float4*)&wl2[cb][k][ct*4];
      float4 vb = *(const float4*)&wl2[cb][k][256+ct*4];
      float xr4[4] = {xa.x,xa.y,xa.z,xa.w};
      float yr4[4] = {ya.x,ya.y,ya.z,ya.w};
      float wc8[8] = {wa.x,wa.y,wa.z,wa.w,wb.x,wb.y,wb.z,wb.w};
      float vc8[8] = {va.x,va.y,va.z,va.w,vb.x,vb.y,vb.z,vb.w};
      #pragma unroll
      for (int r = 0; r < 4; r++)
        #pragma unroll
        for (int j = 0; j < 8; j++)
          acc[r][j] += xr4[r]*wc8[j] + yr4[r]*vc8[j];
    }
    if (c < 63){
      wl1[nb][0][tid]=a0.x; wl1[nb][1][tid]=a0.y; wl1[nb][2][tid]=a0.z; wl1[nb][3][tid]=a0.w;
      wl1[nb][4][tid]=a1.x; wl1[nb][5][tid]=a1.y; wl1[nb][6][tid]=a1.z; wl1[nb][7][tid]=a1.w;
      wl2[nb][0][tid]=f0.x; wl2[nb][1][tid]=f0.y; wl2[nb][2][tid]=f0.z; wl2[nb][3][tid]=f0.w;
      wl2[nb][4][tid]=f1.x; wl2[nb][5][tid]=f1.y; wl2[nb][6][tid]=f1.z; wl2[nb][7][tid]=f1.w;
      if (tid < 128){
        xdst[nb][xkg*4+0][xrow]=xv.x; xdst[nb][xkg*4+1][xrow]=xv.y;
        xdst[nb][xkg*4+2][xrow]=xv.z; xdst[nb][xkg*4+3][xrow]=xv.w;
      }
    }
    __syncthreads();
  }

  float bias[8];
  {
    float4 p0 = *(const float4*)(b1 + ct * 4);
    float4 p1 = *(const float4*)(b1 + 256 + ct * 4);
    float4 q0 = *(const float4*)(b2 + ct * 4);
    float4 q1 = *(const float4*)(b2 + 256 + ct * 4);
    bias[0]=p0.x+q0.x; bias[1]=p0.y+q0.y; bias[2]=p0.z+q0.z; bias[3]=p0.w+q0.w;
    bias[4]=p1.x+q1.x; bias[5]=p1.y+q1.y; bias[6]=p1.z+q1.z; bias[7]=p1.w+q1.w;
  }
  // all ctx reads by this block completed before the last barrier; rows are exclusive.
  #pragma unroll
  for (int r = 0; r < 4; r++){
    long row = r0 + rg * 4 + r;
    float4 o0, o1;
    o0.x=acc[r][0]+bias[0]; o0.y=acc[r][1]+bias[1]; o0.z=acc[r][2]+bias[2]; o0.w=acc[r][3]+bias[3];
    o1.x=acc[r][4]+bias[4]; o1.y=acc[r][5]+bias[5]; o1.z=acc[r][6]+bias[6]; o1.w=acc[r][7]+bias[7];
    *(float4*)(outp + row * 512 + ct * 4) = o0;
    *(float4*)(outp + row * 512 + 256 + ct * 4) = o1;
  }
}

extern "C" void kernel_launch(void* const* d_in, const int* in_sizes, int n_in,
                              void* d_out, int out_size, void* d_ws, size_t ws_size,
                              hipStream_t stream) {
  const float* outs  = (const float*)d_in[0];
  const float* emb   = (const float*)d_in[1];
  const float* W_enc = (const float*)d_in[2];
  const float* b_enc = (const float*)d_in[3];
  const float* W_dec = (const float*)d_in[4];
  const float* b_dec = (const float*)d_in[5];
  const float* v     = (const float*)d_in[6];
  const float* W_h2h = (const float*)d_in[7];
  const float* b_h2h = (const float*)d_in[8];
  const float* W_e2h = (const float*)d_in[9];
  const float* b_e2h = (const float*)d_in[10];

  float* out0 = (float*)d_out;                        // (S,B,H) = 16,777,216 f32
  float* outw = out0 + (size_t)Sn * Bn * Hn;          // (S,S,B) = 33,554,432 f32

  // NO d_ws usage. Scratch lives inside d_out's out0 region with phase aliasing:
  //   phase 1: eat [b][k][a] at out0[0..8388608), pat [b][s][a] at out0[8388608..16777216)
  //            (both hold exp2 of the scaled projection)
  //   phase 2 (after score): ctx [q*B+b][E] at out0[0..16777216)
  //   phase 3: final output overwrites out0 (row-exclusive blocks, staged reads, no race)
  float* eat = out0;
  float* pat = out0 + (size_t)8388608;
  float* ctx = out0;

  hipMemsetAsync(outw, 0, (size_t)Sn * Sn * Bn * 4, stream);   // zero masked weights
  proj_kernel<<<512, 512, 0, stream>>>(emb,  W_enc, b_enc, eat);
  proj_kernel<<<512, 512, 0, stream>>>(outs, W_dec, b_dec, pat);
  score_kernel<<<dim3(128, 32), 256, 0, stream>>>(eat, pat, v, outw);
  context_kernel<<<dim3(128, 32), 256, 0, stream>>>(outw, emb, ctx);
  final_kernel<<<1024, 512, 0, stream>>>(outs, ctx, W_h2h, b_h2h, W_e2h, b_e2h, out0);
}